// Round 7
// baseline (1825.801 us; speedup 1.0000x reference)
//
#include <hip/hip_runtime.h>

#define H 65
#define T_STEPS 1024

typedef _Float16 half_t;
typedef _Float16 half2_t __attribute__((ext_vector_type(2)));

// Guaranteed v_dot2_f32_f16
static __device__ __forceinline__ float dot2(half2_t a, half2_t b, float c) {
#if __has_builtin(__builtin_amdgcn_fdot2)
  return __builtin_amdgcn_fdot2(a, b, c, false);
#else
  float d;
  asm("v_dot2_f32_f16 %0, %1, %2, %3" : "=v"(d) : "v"(a), "v"(b), "v"(c));
  return d;
#endif
}

// Quad-lane permute via DPP. 0xB1=[1,0,3,2] (xor1), 0x4E=[2,3,0,1] (xor2)
template <int CTRL>
static __device__ __forceinline__ float qperm(float v) {
  int r = __builtin_amdgcn_update_dpp(0, __builtin_bit_cast(int, v), CTRL, 0xF, 0xF, true);
  return __builtin_bit_cast(float, r);
}

// ds_swizzle BitMode: offset = (xor<<10)|(or<<5)|and(0x1F)
template <int PAT>
static __device__ __forceinline__ float swz(float v) {
  int r = __builtin_amdgcn_ds_swizzle(__builtin_bit_cast(int, v), PAT);
  return __builtin_bit_cast(float, r);
}

#define LOG2E 1.44269504089f
static __device__ __forceinline__ float fast_sigm(float v) {
  float e = __builtin_amdgcn_exp2f(-LOG2E * v);
  return __builtin_amdgcn_rcpf(1.f + e);
}

// select [a,b,c,d][idx], branchless
static __device__ __forceinline__ float pick(int idx, float a, float b, float c, float d) {
  float lo = (idx & 1) ? b : a;
  float hi = (idx & 1) ? d : c;
  return (idx & 2) ? hi : lo;
}

// ============================================================================
// KERNEL A: 1024t, 16 waves/CU (r2-proven residency), TWO rows per block
// (256 blocks = 1/CU = ONE grid round), r2's 8-lane scheme (36 weight VGPRs,
// fits the immovable 64-reg cap of 1024t workgroups).
//
// oct = tid>>3 in [0,128): octs 0..64 -> (l=0, j), octs 65..127 -> (l=1, j<63)
// kq = (tid>>1)&3 quarter-K, g0 = tid&1 gate pair. K-combine: DPP xor2 +
// ds_swizzle xor4; gate exchange DPP xor1. (r2 math, harness-verified.)
//
// ILP-2 via PAIR-INTERLEAVED LDS: per [layer][parity] buffer of 576 bytes,
// single-row half-pair pi (halfs 2pi,2pi+1) of row r lives at byte 8*pi+4*r.
// One ds_read_b128 = {Apair,Bpair,Apair+1,Bpair+1}: feeds BOTH rows' dot2s
// with r2's single-row DS instruction count (9 b128/lane/step -> 72 dot2).
// Element k of part (0=x,1=h), row r: byte (part?288:0)+8*(k>>1)+4*r+2*(k&1).
//
// Missing units (l=1, j=63,64): EC on wave 15 (r2 verbatim, b64 reads = both
// rows). x staging on wave 14, distance-2 prefetch, both rows.
// Pipeline: L0 computes t=s, L1 computes t=s-1. One barrier/step.
// ============================================================================
__global__
__attribute__((amdgpu_flat_work_group_size(1024, 1024)))
void lstm_fused_a(
    const float* __restrict__ x,
    const float* __restrict__ wih0, const float* __restrict__ whh0,
    const float* __restrict__ bih0, const float* __restrict__ bhh0,
    const float* __restrict__ wih1, const float* __restrict__ whh1,
    const float* __restrict__ bih1, const float* __restrict__ bhh1,
    const float* __restrict__ wlin, const float* __restrict__ blin,
    float* __restrict__ out)
{
  // xh2[layer][parity][576 bytes]: interleaved as documented above.
  __shared__ __align__(16) unsigned char xh2[2][2][576];
  __shared__ float h1f[2][H];

  const int tid = threadIdx.x;

  const int oct = tid >> 3;
  const int l  = (oct >= 65) ? 1 : 0;
  const int j  = oct - 65 * l;
  const int kq = (tid >> 1) & 3;
  const int g0 = tid & 1;
  const bool gz = (g0 == 0);
  const float mreg = gz ? 2.f : 1.f;  // gate g0+2 is tanh (g~) iff g0==0
  const float msub = mreg - 1.f;

  // ---- regular weights: 2 gate-columns x quarter-K = 36 half2 VGPRs ----
  // (r2 verbatim; shared by BOTH rows)
  half2_t w[2][18];
  float hb[2];  // 0.25*bias; 4-way K-combine restores full bias
  {
    const float* wi = l ? wih1 : wih0;
    const float* wh = l ? whh1 : whh0;
    const float* bi = l ? bih1 : bih0;
    const float* bh = l ? bhh1 : bhh0;
#pragma unroll
    for (int cc = 0; cc < 2; ++cc) {
      const int row = (g0 + 2 * cc) * H + j;
      hb[cc] = 0.25f * (bi[row] + bh[row]);
      const float* wiR = wi + row * H;
      const float* whR = wh + row * H;
#pragma unroll
      for (int pp = 0; pp < 18; ++pp) {
        const int bp0 = 36 * kq + 2 * pp;
        const int bp1 = bp0 + 1;
        float e0 = (bp0 < 65) ? wiR[bp0] : ((bp0 >= 72 && bp0 < 137) ? whR[bp0 - 72] : 0.f);
        float e1 = (bp1 < 65) ? wiR[bp1] : ((bp1 >= 72 && bp1 < 137) ? whR[bp1 - 72] : 0.f);
        half2_t v = {(half_t)e0, (half_t)e1};
        w[cc][pp] = v;
      }
    }
  }

  // ---- EC: extra columns (l=1, j=63/64), wave 15, both rows ----
  const bool isW7 = (tid >= 960);
  const int  w7   = tid - 960;
  const int  ec   = w7 >> 3;
  const int  ck   = w7 & 7;
  const int  side = ck >> 2;
  const int  sck  = ck & 3;
  // old single-row byte off = side*144 + 36*sck; interleaved base = 2x
  const int  ecoff2 = 2 * (side * 144 + 36 * sck);
  half2_t ecw[9];
  float ecbias = 0.f;
  float cecA = 0.f, cecB = 0.f;
  if (isW7) {
    const int gec = ec & 3;
    const int jec = 63 + (ec >> 2);
    const int row = gec * H + jec;
    const float* src = (side ? whh1 : wih1) + row * H;
#pragma unroll
    for (int i = 0; i < 9; ++i) {
      int es = 9 * sck + i;
      float e0 = (es < 33) ? src[2 * es] : 0.f;
      float e1 = (es < 33 && 2 * es + 1 < H) ? src[2 * es + 1] : 0.f;
      half2_t v = {(half_t)e0, (half_t)e1};
      ecw[i] = v;
    }
    if (ck == 0) ecbias = bih1[row] + bhh1[row];
  } else {
#pragma unroll
    for (int i = 0; i < 9; ++i) {
      half2_t z = {(half_t)0.f, (half_t)0.f};
      ecw[i] = z;
    }
  }

  // ---- loaders: wave 14 stages BOTH rows' x (distance-2 pipeline) ----
  const bool isW6 = (tid >= 896) && (tid < 960);
  const int  u    = tid - 896;
  // interleaved byte offsets for x elem u, rows A/B
  const int  uoffA = 8 * (u >> 1) + 2 * (u & 1);

  // ---- zero LDS (initial h,c=0; pads stay 0 forever) ----
  for (int i = tid; i < 2 * 2 * 576; i += 1024) ((unsigned char*)xh2)[i] = 0;
  __syncthreads();

  const float* xrowA = x + (size_t)(2 * blockIdx.x)     * (size_t)(T_STEPS * H);
  const float* xrowB = x + (size_t)(2 * blockIdx.x + 1) * (size_t)(T_STEPS * H);
  float nA = 0.f, nA64 = 0.f, nB = 0.f, nB64 = 0.f;
  if (isW6) {
    unsigned char* d0 = &xh2[0][0][0];
    *(half_t*)(d0 + uoffA)     = (half_t)xrowA[u];
    *(half_t*)(d0 + uoffA + 4) = (half_t)xrowB[u];
    if (u == 0) {
      *(half_t*)(d0 + 256)     = (half_t)xrowA[64];  // elem 64: pair 32 slot 0
      *(half_t*)(d0 + 260)     = (half_t)xrowB[64];
    }
    nA = xrowA[H + u];
    nB = xrowB[H + u];
    if (u == 0) { nA64 = xrowA[H + 64]; nB64 = xrowB[H + 64]; }
  }
  __syncthreads();

  float cstA = 0.f, cstB = 0.f;  // cell states (replicated across 8 unit lanes)

  for (int s = 0; s <= T_STEPS; ++s) {
    const int p = s & 1;

    // distance-2 global prefetch
    float fA = 0.f, fA64 = 0.f, fB = 0.f, fB64 = 0.f;
    if (isW6 && (s + 2 < T_STEPS)) {
      const float* xrA = xrowA + (size_t)(s + 2) * H;
      const float* xrB = xrowB + (size_t)(s + 2) * H;
      fA = xrA[u];
      fB = xrB[u];
      if (u == 0) { fA64 = xrA[64]; fB64 = xrB[64]; }
    }

    const bool act = l ? (s >= 1) : (s < T_STEPS);
    if (act) {
      // lane's quarter: interleaved bytes [144*kq, 144*kq+144) = 9 x b128
      const unsigned char* xb = &xh2[l][p][0] + 144 * kq;
      float a0A = hb[0], a1A = hb[1];
      float a0B = hb[0], a1B = hb[1];
#pragma unroll
      for (int c = 0; c < 9; ++c) {
        uint4 qv = ((const uint4*)xb)[c];
        half2_t pA0 = __builtin_bit_cast(half2_t, qv.x);  // row A, pair 2c
        half2_t pB0 = __builtin_bit_cast(half2_t, qv.y);  // row B, pair 2c
        half2_t pA1 = __builtin_bit_cast(half2_t, qv.z);  // row A, pair 2c+1
        half2_t pB1 = __builtin_bit_cast(half2_t, qv.w);  // row B, pair 2c+1
        a0A = dot2(pA0, w[0][2 * c + 0], a0A);
        a0B = dot2(pB0, w[0][2 * c + 0], a0B);
        a1A = dot2(pA0, w[1][2 * c + 0], a1A);
        a1B = dot2(pB0, w[1][2 * c + 0], a1B);
        a0A = dot2(pA1, w[0][2 * c + 1], a0A);
        a0B = dot2(pB1, w[0][2 * c + 1], a0B);
        a1A = dot2(pA1, w[1][2 * c + 1], a1A);
        a1B = dot2(pB1, w[1][2 * c + 1], a1B);
      }
      // K-combine across the 4 kq lanes: tid^2 via DPP, tid^4 via ds_swizzle
      a0A += qperm<0x4E>(a0A);
      a1A += qperm<0x4E>(a1A);
      a0B += qperm<0x4E>(a0B);
      a1B += qperm<0x4E>(a1B);
      a0A += swz<0x101F>(a0A);
      a1A += swz<0x101F>(a1A);
      a0B += swz<0x101F>(a0B);
      a1B += swz<0x101F>(a1B);
      float e0A = fast_sigm(a0A);
      float e1A = mreg * fast_sigm(mreg * a1A) - msub;  // tanh via 2σ(2x)-1
      float e0B = fast_sigm(a0B);
      float e1B = mreg * fast_sigm(mreg * a1B) - msub;
      float p0A = qperm<0xB1>(e0A);  // gate-pair exchange (tid^1)
      float p1A = qperm<0xB1>(e1A);
      float p0B = qperm<0xB1>(e0B);
      float p1B = qperm<0xB1>(e1B);
      float ivA = gz ? e0A : p0A, fvA = gz ? p0A : e0A;
      float gvA = gz ? e1A : p1A, ovA = gz ? p1A : e1A;
      float ivB = gz ? e0B : p0B, fvB = gz ? p0B : e0B;
      float gvB = gz ? e1B : p1B, ovB = gz ? p1B : e1B;
      cstA = fvA * cstA + ivA * gvA;
      cstB = fvB * cstB + ivB * gvB;
      float thA = 2.f * fast_sigm(2.f * cstA) - 1.f;
      float thB = 2.f * fast_sigm(2.f * cstB) - 1.f;
      float hvA = ovA * thA;
      float hvB = ovB * thB;
      if ((tid & 7) == 0) {
        half_t hA = (half_t)hvA;
        half_t hB = (half_t)hvB;
        const int hoff = 288 + 8 * (j >> 1) + 2 * (j & 1);  // h-part elem j, row A
        const int xoff = 8 * (j >> 1) + 2 * (j & 1);        // x-part elem j, row A
        if (l == 0) {
          unsigned char* d00 = &xh2[0][p ^ 1][0];
          unsigned char* d10 = &xh2[1][p ^ 1][0];
          *(half_t*)(d00 + hoff)     = hA;  // own recurrence
          *(half_t*)(d00 + hoff + 4) = hB;
          *(half_t*)(d10 + xoff)     = hA;  // layer-1 input
          *(half_t*)(d10 + xoff + 4) = hB;
        } else {
          unsigned char* d11 = &xh2[1][p ^ 1][0];
          *(half_t*)(d11 + hoff)     = hA;
          *(half_t*)(d11 + hoff + 4) = hB;
          if (s == T_STEPS) { h1f[0][j] = hvA; h1f[1][j] = hvB; }
        }
      }
    }

    // ---- EC path (wave 15): columns (l=1, j=63,64), both rows ----
    if (isW7 && s >= 1) {
      const unsigned char* xb1 = &xh2[1][p][0];
      float aecA = ecbias, aecB = ecbias;
#pragma unroll
      for (int i = 0; i < 9; ++i) {
        uint2 qv = *(const uint2*)(xb1 + ecoff2 + 8 * i);  // {rowA dword, rowB dword}
        aecA = dot2(__builtin_bit_cast(half2_t, qv.x), ecw[i], aecA);
        aecB = dot2(__builtin_bit_cast(half2_t, qv.y), ecw[i], aecB);
      }
      aecA += swz<0x041F>(aecA);  // xor1
      aecB += swz<0x041F>(aecB);
      aecA += swz<0x081F>(aecA);  // xor2
      aecB += swz<0x081F>(aecB);
      aecA += swz<0x101F>(aecA);  // xor4: full column preact in all 8 lanes
      aecB += swz<0x101F>(aecB);
      const int gec = ec & 3;
      float me = (gec == 2) ? 2.f : 1.f;
      float AA = me * fast_sigm(me * aecA) - (me - 1.f);
      float AB = me * fast_sigm(me * aecB) - (me - 1.f);
      float BvA = swz<0x201F>(AA);   // act of ec^1
      float BvB = swz<0x201F>(AB);
      float CvA = swz<0x401F>(AA);   // act of ec^2
      float CvB = swz<0x401F>(AB);
      float DvA = swz<0x401F>(BvA);  // act of ec^3
      float DvB = swz<0x401F>(BvB);
      float ivA2 = pick(gec ^ 0, AA, BvA, CvA, DvA);
      float fvA2 = pick(gec ^ 1, AA, BvA, CvA, DvA);
      float gvA2 = pick(gec ^ 2, AA, BvA, CvA, DvA);
      float ovA2 = pick(gec ^ 3, AA, BvA, CvA, DvA);
      float ivB2 = pick(gec ^ 0, AB, BvB, CvB, DvB);
      float fvB2 = pick(gec ^ 1, AB, BvB, CvB, DvB);
      float gvB2 = pick(gec ^ 2, AB, BvB, CvB, DvB);
      float ovB2 = pick(gec ^ 3, AB, BvB, CvB, DvB);
      cecA = fvA2 * cecA + ivA2 * gvA2;
      cecB = fvB2 * cecB + ivB2 * gvB2;
      float hecA = ovA2 * (2.f * fast_sigm(2.f * cecA) - 1.f);
      float hecB = ovB2 * (2.f * fast_sigm(2.f * cecB) - 1.f);
      if (ck == 0 && (ec & 3) == 0) {  // w7==0 -> j63, w7==32 -> j64
        const int jec = 63 + (ec >> 2);
        const int hoff = 288 + 8 * (jec >> 1) + 2 * (jec & 1);
        unsigned char* d11 = &xh2[1][p ^ 1][0];
        *(half_t*)(d11 + hoff)     = (half_t)hecA;
        *(half_t*)(d11 + hoff + 4) = (half_t)hecB;
        if (s == T_STEPS) { h1f[0][jec] = hecA; h1f[1][jec] = hecB; }
      }
    }

    // stage x_{s+1} for both rows; shift prefetch pipeline
    if (isW6 && (s + 1 < T_STEPS)) {
      unsigned char* d0 = &xh2[0][p ^ 1][0];
      *(half_t*)(d0 + uoffA)     = (half_t)nA;
      *(half_t*)(d0 + uoffA + 4) = (half_t)nB;
      if (u == 0) {
        *(half_t*)(d0 + 256) = (half_t)nA64;
        *(half_t*)(d0 + 260) = (half_t)nB64;
      }
      nA = fA; nA64 = fA64; nB = fB; nB64 = fB64;
    }
    __syncthreads();
  }

  // ---- output projection ----
  if (tid == 0) {
    float acc0 = blin[0], acc1 = blin[0];
    for (int jj = 0; jj < H; ++jj) {
      acc0 += h1f[0][jj] * wlin[jj];
      acc1 += h1f[1][jj] * wlin[jj];
    }
    out[2 * blockIdx.x]     = acc0;
    out[2 * blockIdx.x + 1] = acc1;
  }
}

// ============================================================================
// KERNEL B: r6's proven fallback (1402us, 88 regs, spill-free). Unchanged.
// ============================================================================
__global__ __launch_bounds__(512, 1) void lstm_fused_512(
    const float* __restrict__ x,
    const float* __restrict__ wih0, const float* __restrict__ whh0,
    const float* __restrict__ bih0, const float* __restrict__ bhh0,
    const float* __restrict__ wih1, const float* __restrict__ whh1,
    const float* __restrict__ bih1, const float* __restrict__ bhh1,
    const float* __restrict__ wlin, const float* __restrict__ blin,
    float* __restrict__ out)
{
  __shared__ __align__(16) half_t xh[2][2][2][144];
  __shared__ float h1f[2][H];

  const int tid = threadIdx.x;

  const int quad = tid >> 2;
  const int l  = (quad >= 65) ? 1 : 0;
  const int j  = quad - 65 * l;
  const int kh = (tid >> 1) & 1;
  const int g0 = tid & 1;
  const bool gz = (g0 == 0);
  const float mreg = gz ? 2.f : 1.f;
  const float msub = mreg - 1.f;

  half2_t w[2][33];
  float hb[2];
  {
    const float* wi = l ? wih1 : wih0;
    const float* wh = l ? whh1 : whh0;
    const float* bi = l ? bih1 : bih0;
    const float* bh = l ? bhh1 : bhh0;
#pragma unroll
    for (int cc = 0; cc < 2; ++cc) {
      const int row = (g0 + 2 * cc) * H + j;
      hb[cc] = 0.5f * (bi[row] + bh[row]);
      const float* src = (kh ? wh : wi) + row * H;
#pragma unroll
      for (int pp = 0; pp < 33; ++pp) {
        float e0 = src[2 * pp];
        float e1 = (2 * pp + 1 < H) ? src[2 * pp + 1] : 0.f;
        half2_t v = {(half_t)e0, (half_t)e1};
        w[cc][pp] = v;
      }
    }
  }

  const bool isEC = (tid >= 384);
  const int  e6   = tid & 63;
  const int  ecR  = (tid >> 6) & 1;
  const int  ec   = e6 >> 3;
  const int  ck   = e6 & 7;
  const int  side = ck >> 2;
  const int  sck  = ck & 3;
  const int  ecoff = side * 144 + 36 * sck;
  half2_t ecw[9];
  float ecbias = 0.f;
  float cec = 0.f;
  if (isEC) {
    const int gec = ec & 3;
    const int jec = 63 + (ec >> 2);
    const int row = gec * H + jec;
    const float* src = (side ? whh1 : wih1) + row * H;
#pragma unroll
    for (int i = 0; i < 9; ++i) {
      int es = 9 * sck + i;
      float e0 = (es < 33) ? src[2 * es] : 0.f;
      float e1 = (es < 33 && 2 * es + 1 < H) ? src[2 * es + 1] : 0.f;
      half2_t v = {(half_t)e0, (half_t)e1};
      ecw[i] = v;
    }
    if (ck == 0) ecbias = bih1[row] + bhh1[row];
  } else {
#pragma unroll
    for (int i = 0; i < 9; ++i) {
      half2_t z = {(half_t)0.f, (half_t)0.f};
      ecw[i] = z;
    }
  }

  const bool isST = (tid < 64);
  const int  u    = tid;

  for (int i = tid; i < 2 * 2 * 2 * 144; i += 512) ((half_t*)xh)[i] = (half_t)0.f;
  __syncthreads();

  const float* xrowA = x + (size_t)(2 * blockIdx.x)     * (size_t)(T_STEPS * H);
  const float* xrowB = x + (size_t)(2 * blockIdx.x + 1) * (size_t)(T_STEPS * H);
  float nA = 0.f, nA64 = 0.f, nB = 0.f, nB64 = 0.f;
  if (isST) {
    xh[0][0][0][u] = (half_t)xrowA[u];
    xh[1][0][0][u] = (half_t)xrowB[u];
    if (u == 0) {
      xh[0][0][0][64] = (half_t)xrowA[64];
      xh[1][0][0][64] = (half_t)xrowB[64];
    }
    nA = xrowA[H + u];
    nB = xrowB[H + u];
    if (u == 0) { nA64 = xrowA[H + 64]; nB64 = xrowB[H + 64]; }
  }
  __syncthreads();

  float cstA = 0.f, cstB = 0.f;

  for (int s = 0; s <= T_STEPS; ++s) {
    const int p = s & 1;

    float fA = 0.f, fA64 = 0.f, fB = 0.f, fB64 = 0.f;
    if (isST && (s + 2 < T_STEPS)) {
      const float* xrA = xrowA + (size_t)(s + 2) * H;
      const float* xrB = xrowB + (size_t)(s + 2) * H;
      fA = xrA[u];
      fB = xrB[u];
      if (u == 0) { fA64 = xrA[64]; fB64 = xrB[64]; }
    }

    const bool act = l ? (s >= 1) : (s < T_STEPS);
    if (act) {
      const half_t* xbA = &xh[0][l][p][0] + 72 * kh;
      const half_t* xbB = &xh[1][l][p][0] + 72 * kh;
      float a0A = hb[0], a1A = hb[1];
      float a0B = hb[0], a1B = hb[1];
#pragma unroll
      for (int c = 0; c < 8; ++c) {
        uint4 qA = ((const uint4*)xbA)[c];
        uint4 qB = ((const uint4*)xbB)[c];
        half2_t xA0 = __builtin_bit_cast(half2_t, qA.x);
        half2_t xA1 = __builtin_bit_cast(half2_t, qA.y);
        half2_t xA2 = __builtin_bit_cast(half2_t, qA.z);
        half2_t xA3 = __builtin_bit_cast(half2_t, qA.w);
        half2_t xB0 = __builtin_bit_cast(half2_t, qB.x);
        half2_t xB1 = __builtin_bit_cast(half2_t, qB.y);
        half2_t xB2 = __builtin_bit_cast(half2_t, qB.z);
        half2_t xB3 = __builtin_bit_cast(half2_t, qB.w);
        a0A = dot2(xA0, w[0][4 * c + 0], a0A);
        a0B = dot2(xB0, w[0][4 * c + 0], a0B);
        a1A = dot2(xA0, w[1][4 * c + 0], a1A);
        a1B = dot2(xB0, w[1][4 * c + 0], a1B);
        a0A = dot2(xA1, w[0][4 * c + 1], a0A);
        a0B = dot2(xB1, w[0][4 * c + 1], a0B);
        a1A = dot2(xA1, w[1][4 * c + 1], a1A);
        a1B = dot2(xB1, w[1][4 * c + 1], a1B);
        a0A = dot2(xA2, w[0][4 * c + 2], a0A);
        a0B = dot2(xB2, w[0][4 * c + 2], a0B);
        a1A = dot2(xA2, w[1][4 * c + 2], a1A);
        a1B = dot2(xB2, w[1][4 * c + 2], a1B);
        a0A = dot2(xA3, w[0][4 * c + 3], a0A);
        a0B = dot2(xB3, w[0][4 * c + 3], a0B);
        a1A = dot2(xA3, w[1][4 * c + 3], a1A);
        a1B = dot2(xB3, w[1][4 * c + 3], a1B);
      }
      {
        half2_t xtA = *(const half2_t*)(xbA + 64);
        half2_t xtB = *(const half2_t*)(xbB + 64);
        a0A = dot2(xtA, w[0][32], a0A);
        a0B = dot2(xtB, w[0][32], a0B);
        a1A = dot2(xtA, w[1][32], a1A);
        a1B = dot2(xtB, w[1][32], a1B);
      }
      a0A += qperm<0x4E>(a0A);
      a1A += qperm<0x4E>(a1A);
      a0B += qperm<0x4E>(a0B);
      a1B += qperm<0x4E>(a1B);
      float e0A = fast_sigm(a0A);
      float e1A = mreg * fast_sigm(mreg * a1A) - msub;
      float e0B = fast_sigm(a0B);
      float e1B = mreg * fast_sigm(mreg * a1B) - msub;
      float p0A = qperm<0xB1>(e0A);
      float p1A = qperm<0xB1>(e1A);
      float p0B = qperm<0xB1>(e0B);
      float p1B = qperm<0xB1>(e1B);
      float ivA = gz ? e0A : p0A, fvA = gz ? p0A : e0A;
      float gvA = gz ? e1A : p1A, ovA = gz ? p1A : e1A;
      float ivB = gz ? e0B : p0B, fvB = gz ? p0B : e0B;
      float gvB = gz ? e1B : p1B, ovB = gz ? p1B : e1B;
      cstA = fvA * cstA + ivA * gvA;
      cstB = fvB * cstB + ivB * gvB;
      float thA = 2.f * fast_sigm(2.f * cstA) - 1.f;
      float thB = 2.f * fast_sigm(2.f * cstB) - 1.f;
      float hvA = ovA * thA;
      float hvB = ovB * thB;
      if ((tid & 3) == 0) {
        half_t hA = (half_t)hvA;
        half_t hB = (half_t)hvB;
        if (l == 0) {
          xh[0][0][p ^ 1][72 + j] = hA;
          xh[0][1][p ^ 1][j]      = hA;
          xh[1][0][p ^ 1][72 + j] = hB;
          xh[1][1][p ^ 1][j]      = hB;
        } else {
          xh[0][1][p ^ 1][72 + j] = hA;
          xh[1][1][p ^ 1][72 + j] = hB;
          if (s == T_STEPS) { h1f[0][j] = hvA; h1f[1][j] = hvB; }
        }
      }
    }

    if (isEC && s >= 1) {
      const char* xb1 = (const char*)&xh[ecR][1][p][0];
      float aec = ecbias;
#pragma unroll
      for (int i = 0; i < 9; ++i) {
        unsigned qv = *(const unsigned*)(xb1 + ecoff + 4 * i);
        aec = dot2(__builtin_bit_cast(half2_t, qv), ecw[i], aec);
      }
      aec += swz<0x041F>(aec);
      aec += swz<0x081F>(aec);
      aec += swz<0x101F>(aec);
      const int gec = ec & 3;
      float me = (gec == 2) ? 2.f : 1.f;
      float A  = me * fast_sigm(me * aec) - (me - 1.f);
      float Bv = swz<0x201F>(A);
      float Cv = swz<0x401F>(A);
      float Dv = swz<0x401F>(Bv);
      float iv2 = pick(gec ^ 0, A, Bv, Cv, Dv);
      float fv2 = pick(gec ^ 1, A, Bv, Cv, Dv);
      float gv2 = pick(gec ^ 2, A, Bv, Cv, Dv);
      float ov2 = pick(gec ^ 3, A, Bv, Cv, Dv);
      cec = fv2 * cec + iv2 * gv2;
      float hec = ov2 * (2.f * fast_sigm(2.f * cec) - 1.f);
      if (ck == 0 && (ec & 3) == 0) {
        const int jec = 63 + (ec >> 2);
        xh[ecR][1][p ^ 1][72 + jec] = (half_t)hec;
        if (s == T_STEPS) h1f[ecR][jec] = hec;
      }
    }

    if (isST && (s + 1 < T_STEPS)) {
      half_t* dA = &xh[0][0][p ^ 1][0];
      half_t* dB = &xh[1][0][p ^ 1][0];
      dA[u] = (half_t)nA;
      dB[u] = (half_t)nB;
      if (u == 0) { dA[64] = (half_t)nA64; dB[64] = (half_t)nB64; }
      nA = fA; nA64 = fA64; nB = fB; nB64 = fB64;
    }
    __syncthreads();
  }

  if (tid == 0) {
    float acc0 = blin[0], acc1 = blin[0];
    for (int jj = 0; jj < H; ++jj) {
      acc0 += h1f[0][jj] * wlin[jj];
      acc1 += h1f[1][jj] * wlin[jj];
    }
    out[2 * blockIdx.x]     = acc0;
    out[2 * blockIdx.x + 1] = acc1;
  }
}

extern "C" void kernel_launch(void* const* d_in, const int* in_sizes, int n_in,
                              void* d_out, int out_size, void* d_ws, size_t ws_size,
                              hipStream_t stream) {
  const float* x    = (const float*)d_in[0];
  const float* wih0 = (const float*)d_in[1];
  const float* whh0 = (const float*)d_in[2];
  const float* bih0 = (const float*)d_in[3];
  const float* bhh0 = (const float*)d_in[4];
  const float* wih1 = (const float*)d_in[5];
  const float* whh1 = (const float*)d_in[6];
  const float* bih1 = (const float*)d_in[7];
  const float* bhh1 = (const float*)d_in[8];
  const float* wlin = (const float*)d_in[9];
  const float* blin = (const float*)d_in[10];
  float* out = (float*)d_out;

  // Host-side one-time dispatch: use kernel A unless it spilled meaningfully
  // (>40 bytes of scratch -> per-step reload tax; then B's 1402us is better).
  static int useA = -1;
  if (useA < 0) {
    hipFuncAttributes a{};
    if (hipFuncGetAttributes(&a, reinterpret_cast<const void*>(&lstm_fused_a)) == hipSuccess &&
        a.localSizeBytes <= 40) {
      useA = 1;
    } else {
      useA = 0;
    }
  }

  if (useA) {
    lstm_fused_a<<<256, 1024, 0, stream>>>(x, wih0, whh0, bih0, bhh0,
                                           wih1, whh1, bih1, bhh1, wlin, blin, out);
  } else {
    lstm_fused_512<<<256, 512, 0, stream>>>(x, wih0, whh0, bih0, bhh0,
                                            wih1, whh1, bih1, bhh1, wlin, blin, out);
  }
}

// Round 8
// 1420.047 us; speedup vs baseline: 1.2857x; 1.2857x over previous
//
#include <hip/hip_runtime.h>

#define H 65
#define T_STEPS 1024

typedef _Float16 half_t;
typedef _Float16 half2_t __attribute__((ext_vector_type(2)));

// Guaranteed v_dot2_f32_f16
static __device__ __forceinline__ float dot2(half2_t a, half2_t b, float c) {
#if __has_builtin(__builtin_amdgcn_fdot2)
  return __builtin_amdgcn_fdot2(a, b, c, false);
#else
  float d;
  asm("v_dot2_f32_f16 %0, %1, %2, %3" : "=v"(d) : "v"(a), "v"(b), "v"(c));
  return d;
#endif
}

// Quad-lane permute via DPP. 0xB1=[1,0,3,2] (xor1), 0x4E=[2,3,0,1] (xor2)
template <int CTRL>
static __device__ __forceinline__ float qperm(float v) {
  int r = __builtin_amdgcn_update_dpp(0, __builtin_bit_cast(int, v), CTRL, 0xF, 0xF, true);
  return __builtin_bit_cast(float, r);
}

// ds_swizzle BitMode: offset = (xor<<10)|(or<<5)|and(0x1F)
template <int PAT>
static __device__ __forceinline__ float swz(float v) {
  int r = __builtin_amdgcn_ds_swizzle(__builtin_bit_cast(int, v), PAT);
  return __builtin_bit_cast(float, r);
}

#define LOG2E 1.44269504089f
static __device__ __forceinline__ float fast_sigm(float v) {
  float e = __builtin_amdgcn_exp2f(-LOG2E * v);
  return __builtin_amdgcn_rcpf(1.f + e);
}

// select [a,b,c,d][idx], branchless
static __device__ __forceinline__ float pick(int idx, float a, float b, float c, float d) {
  float lo = (idx & 1) ? b : a;
  float hi = (idx & 1) ? d : c;
  return (idx & 2) ? hi : lo;
}

// r0's structure (best measured per-row: 4-lane scheme + 4 waves/SIMD) with the
// register overflow moved from scratch to LDS.
//
// Evidence (r0-r7): blocks co-reside on a CU ONLY at <=64 VGPRs (r0 paired at
// 64; 88/92/96-reg 512t blocks never paired). The 4-lane scheme needs ~105
// regs if everything lives in registers -> r0 spilled 41 dwords to scratch and
// STILL beat every spill-free config since (1584 cy/row), because 4 waves/SIMD
// out-hides everything. Fix the one flaw: instead of letting the allocator
// spill 41 dwords to scratch (43 MB traffic, 200-900cy reloads), we explicitly
// place the a1-gate weight column w1[0..27] (28 dwords/lane) and the EC
// weights (9 dwords) in LDS:
//   wlds[7][512] uint4, chunk-major: read wlds[c][tid] -> consecutive-lane
//   16B = conflict-free ds_read_b128. 57.3 KB.
//   eclds[2][64] uint4 + ecl1[64]: EC weights, wave-7 lanes only. 2.3 KB.
// Register-resident: w0[33] (a0 column) + w1t[5] (a1 tail pairs 28..32) = 38
// weight VGPRs + ~26 state/addr -> ~64 demand at the (512,4)-forced 64 cap.
// LDS/block ~61 KB <= 64 KB static limit; 2 blocks = 122 KB <= 160 KB LDS/CU
// -> 2 blocks/CU (r0-proven at 64 regs) = 4 waves/SIMD, one grid round.
// Per-step weight re-read: 114 KB/CU ~ 1000 cy LDS BW, below the issue floor.
//
// Quad scheme (r0 verbatim): quad = tid>>2 -> unit (l,j): quads 0..64 = (0,j),
// 65..127 = (1, j=0..62). kh=(tid>>1)&1 K-half, g0=tid&1 gate pair. DPP xor2
// K-combine, xor1 gate-pair exchange. EC (l=1, j=63,64) on wave 7; x staging
// on wave 6 (distance-2). h double-buffered by parity. L0 t=s, L1 t=s-1.
__global__ __launch_bounds__(512, 4) void lstm_fused(
    const float* __restrict__ x,
    const float* __restrict__ wih0, const float* __restrict__ whh0,
    const float* __restrict__ bih0, const float* __restrict__ bhh0,
    const float* __restrict__ wih1, const float* __restrict__ whh1,
    const float* __restrict__ bih1, const float* __restrict__ bhh1,
    const float* __restrict__ wlin, const float* __restrict__ blin,
    float* __restrict__ out)
{
  __shared__ __align__(16) uint4 wlds[7][512];    // w1 pairs 0..27, chunk-major
  __shared__ __align__(16) uint4 eclds[2][64];    // EC pairs 0..7
  __shared__ float ecl1[64];                      // EC pair 8
  // xh[layer][parity][144]: 0..64 input part, 65..71 pad, 72..136 h, 137..143 pad
  __shared__ __align__(16) half_t xh[2][2][144];
  __shared__ float h1f[H];

  const int tid = threadIdx.x;
  const int b   = blockIdx.x;

  const int quad = tid >> 2;
  const int l  = (quad >= 65) ? 1 : 0;
  const int j  = quad - 65 * l;
  const int kh = (tid >> 1) & 1;
  const int g0 = tid & 1;
  const bool gz = (g0 == 0);
  const float mreg = gz ? 2.f : 1.f;  // gate g0+2 is tanh (g~) iff g0==0
  const float msub = mreg - 1.f;

  // ---- weights: a0 column fully in regs; a1 column body -> LDS ----
  half2_t w0[33];   // gate g0, all 33 pairs
  half2_t w1t[5];   // gate g0+2, pairs 28..32
  float hb[2];      // 0.5*bias; xor2 K-combine restores full bias
  {
    const float* wi = l ? wih1 : wih0;
    const float* wh = l ? whh1 : whh0;
    const float* bi = l ? bih1 : bih0;
    const float* bh = l ? bhh1 : bhh0;
    // cc = 0 -> registers
    {
      const int row = g0 * H + j;
      hb[0] = 0.5f * (bi[row] + bh[row]);
      const float* src = (kh ? wh : wi) + row * H;
#pragma unroll
      for (int pp = 0; pp < 33; ++pp) {
        float e0 = src[2 * pp];
        float e1 = (2 * pp + 1 < H) ? src[2 * pp + 1] : 0.f;
        half2_t v = {(half_t)e0, (half_t)e1};
        w0[pp] = v;
      }
    }
    // cc = 1 -> pairs 0..27 to LDS (7 chunks of 4), pairs 28..32 to regs
    {
      const int row = (g0 + 2) * H + j;
      hb[1] = 0.5f * (bi[row] + bh[row]);
      const float* src = (kh ? wh : wi) + row * H;
#pragma unroll
      for (int c7 = 0; c7 < 7; ++c7) {
        unsigned t0, t1, t2, t3;
#pragma unroll
        for (int q = 0; q < 4; ++q) {
          const int pp = 4 * c7 + q;            // pp <= 27 -> 2pp+1 <= 55 < H
          half2_t v = {(half_t)src[2 * pp], (half_t)src[2 * pp + 1]};
          unsigned uv = __builtin_bit_cast(unsigned, v);
          if (q == 0) t0 = uv; else if (q == 1) t1 = uv;
          else if (q == 2) t2 = uv; else t3 = uv;
        }
        uint4 wv = {t0, t1, t2, t3};
        wlds[c7][tid] = wv;
      }
#pragma unroll
      for (int q = 0; q < 5; ++q) {
        const int pp = 28 + q;
        float e0 = src[2 * pp];
        float e1 = (2 * pp + 1 < H) ? src[2 * pp + 1] : 0.f;
        half2_t v = {(half_t)e0, (half_t)e1};
        w1t[q] = v;
      }
    }
  }

  // ---- EC: extra columns (l=1, j=63/64), wave 7; weights -> LDS ----
  const bool isW7 = (tid >= 448);
  const int  w7   = tid - 448;
  const int  ec   = w7 >> 3;
  const int  ck   = w7 & 7;
  const int  side = ck >> 2;
  const int  sck  = ck & 3;
  const int  ecoff = side * 144 + 36 * sck;  // byte offset within xh[1][p]
  float ecbias = 0.f;
  float cec = 0.f;
  if (isW7) {
    const int gec = ec & 3;
    const int jec = 63 + (ec >> 2);
    const int row = gec * H + jec;
    const float* src = (side ? whh1 : wih1) + row * H;
    unsigned t[9];
#pragma unroll
    for (int i = 0; i < 9; ++i) {
      int es = 9 * sck + i;
      float e0 = (es < 33) ? src[2 * es] : 0.f;
      float e1 = (es < 33 && 2 * es + 1 < H) ? src[2 * es + 1] : 0.f;
      half2_t v = {(half_t)e0, (half_t)e1};
      t[i] = __builtin_bit_cast(unsigned, v);
    }
    uint4 e0v = {t[0], t[1], t[2], t[3]};
    uint4 e1v = {t[4], t[5], t[6], t[7]};
    eclds[0][w7] = e0v;
    eclds[1][w7] = e1v;
    ecl1[w7] = __builtin_bit_cast(float, t[8]);
    if (ck == 0) ecbias = bih1[row] + bhh1[row];
  }

  // ---- loaders: wave 6 stages x (distance-2 pipeline) ----
  const bool isW6 = (tid >= 384) && (tid < 448);
  const int  u    = tid - 384;

  // ---- zero xh (initial h,c=0; pads stay 0 forever) ----
  for (int i = tid; i < 2 * 2 * 144; i += 512) ((half_t*)xh)[i] = (half_t)0.f;
  __syncthreads();   // also publishes wlds / eclds

  const float* xrow = x + (size_t)b * (size_t)(T_STEPS * H);
  float nxA = 0.f, nxB = 0.f;
  if (isW6) {
    xh[0][0][u] = (half_t)xrow[u];
    if (u == 0) xh[0][0][64] = (half_t)xrow[64];
    nxA = xrow[H + u];
    if (u == 0) nxB = xrow[H + 64];
  }
  __syncthreads();

  float cst = 0.f;  // cell state (replicated across quad lanes)

  for (int s = 0; s <= T_STEPS; ++s) {
    const int p = s & 1;

    // distance-2 global prefetch (latency hidden across the step)
    float fA = 0.f, fB = 0.f;
    if (isW6 && (s + 2 < T_STEPS)) {
      const float* xr = xrow + (size_t)(s + 2) * H;
      fA = xr[u];
      if (u == 0) fB = xr[64];
    }

    const bool act = l ? (s >= 1) : (s < T_STEPS);
    if (act) {
      const half_t* xb = &xh[l][p][0] + 72 * kh;
      float a0 = hb[0], a1 = hb[1];
#pragma unroll
      for (int c = 0; c < 7; ++c) {
        uint4 qv = ((const uint4*)xb)[c];
        uint4 wv = wlds[c][tid];
        half2_t x0 = __builtin_bit_cast(half2_t, qv.x);
        half2_t x1 = __builtin_bit_cast(half2_t, qv.y);
        half2_t x2 = __builtin_bit_cast(half2_t, qv.z);
        half2_t x3 = __builtin_bit_cast(half2_t, qv.w);
        half2_t w10 = __builtin_bit_cast(half2_t, wv.x);
        half2_t w11 = __builtin_bit_cast(half2_t, wv.y);
        half2_t w12 = __builtin_bit_cast(half2_t, wv.z);
        half2_t w13 = __builtin_bit_cast(half2_t, wv.w);
        a0 = dot2(x0, w0[4 * c + 0], a0);
        a1 = dot2(x0, w10, a1);
        a0 = dot2(x1, w0[4 * c + 1], a0);
        a1 = dot2(x1, w11, a1);
        a0 = dot2(x2, w0[4 * c + 2], a0);
        a1 = dot2(x2, w12, a1);
        a0 = dot2(x3, w0[4 * c + 3], a0);
        a1 = dot2(x3, w13, a1);
      }
      {  // chunk 7: pairs 28..31 (w1 from regs)
        uint4 qv = ((const uint4*)xb)[7];
        half2_t x0 = __builtin_bit_cast(half2_t, qv.x);
        half2_t x1 = __builtin_bit_cast(half2_t, qv.y);
        half2_t x2 = __builtin_bit_cast(half2_t, qv.z);
        half2_t x3 = __builtin_bit_cast(half2_t, qv.w);
        a0 = dot2(x0, w0[28], a0);
        a1 = dot2(x0, w1t[0], a1);
        a0 = dot2(x1, w0[29], a0);
        a1 = dot2(x1, w1t[1], a1);
        a0 = dot2(x2, w0[30], a0);
        a1 = dot2(x2, w1t[2], a1);
        a0 = dot2(x3, w0[31], a0);
        a1 = dot2(x3, w1t[3], a1);
      }
      {  // tail pair 32 (elem 64 + pad)
        half2_t xt = *(const half2_t*)(xb + 64);
        a0 = dot2(xt, w0[32], a0);
        a1 = dot2(xt, w1t[4], a1);
      }
      a0 += qperm<0x4E>(a0);  // K-combine with kh partner
      a1 += qperm<0x4E>(a1);
      float e0 = fast_sigm(a0);
      float e1 = mreg * fast_sigm(mreg * a1) - msub;  // tanh via 2σ(2x)-1
      float p0 = qperm<0xB1>(e0);  // gate-pair exchange
      float p1 = qperm<0xB1>(e1);
      float iv = gz ? e0 : p0;
      float fv = gz ? p0 : e0;
      float gv = gz ? e1 : p1;
      float ov = gz ? p1 : e1;
      cst = fv * cst + iv * gv;
      float th = 2.f * fast_sigm(2.f * cst) - 1.f;
      float hv = ov * th;
      if ((tid & 3) == 0) {
        half_t hh = (half_t)hv;
        if (l == 0) {
          xh[0][p ^ 1][72 + j] = hh;  // own recurrence
          xh[1][p ^ 1][j]      = hh;  // layer-1 input
        } else {
          xh[1][p ^ 1][72 + j] = hh;
          if (s == T_STEPS) h1f[j] = hv;
        }
      }
    }

    // ---- EC path (wave 7 only): columns (l=1, j=63,64) ----
    if (isW7 && s >= 1) {
      const char* xb1 = (const char*)&xh[1][p][0];
      uint4 ev0 = eclds[0][w7];
      uint4 ev1 = eclds[1][w7];
      half2_t ew8 = __builtin_bit_cast(half2_t, ecl1[w7]);
      float aec = ecbias;
#pragma unroll
      for (int i = 0; i < 9; ++i) {
        unsigned qv = *(const unsigned*)(xb1 + ecoff + 4 * i);
        half2_t wv;
        if (i == 0) wv = __builtin_bit_cast(half2_t, ev0.x);
        else if (i == 1) wv = __builtin_bit_cast(half2_t, ev0.y);
        else if (i == 2) wv = __builtin_bit_cast(half2_t, ev0.z);
        else if (i == 3) wv = __builtin_bit_cast(half2_t, ev0.w);
        else if (i == 4) wv = __builtin_bit_cast(half2_t, ev1.x);
        else if (i == 5) wv = __builtin_bit_cast(half2_t, ev1.y);
        else if (i == 6) wv = __builtin_bit_cast(half2_t, ev1.z);
        else if (i == 7) wv = __builtin_bit_cast(half2_t, ev1.w);
        else wv = ew8;
        aec = dot2(__builtin_bit_cast(half2_t, qv), wv, aec);
      }
      aec += swz<0x041F>(aec);  // xor1
      aec += swz<0x081F>(aec);  // xor2
      aec += swz<0x101F>(aec);  // xor4: full column preact in all 8 lanes
      const int gec = ec & 3;
      float me = (gec == 2) ? 2.f : 1.f;
      float A  = me * fast_sigm(me * aec) - (me - 1.f);
      float Bv = swz<0x201F>(A);   // act of ec^1
      float Cv = swz<0x401F>(A);   // act of ec^2
      float Dv = swz<0x401F>(Bv);  // act of ec^3
      float iv2 = pick(gec ^ 0, A, Bv, Cv, Dv);
      float fv2 = pick(gec ^ 1, A, Bv, Cv, Dv);
      float gv2 = pick(gec ^ 2, A, Bv, Cv, Dv);
      float ov2 = pick(gec ^ 3, A, Bv, Cv, Dv);
      cec = fv2 * cec + iv2 * gv2;
      float hec = ov2 * (2.f * fast_sigm(2.f * cec) - 1.f);
      if (ck == 0 && (ec & 3) == 0) {  // w7==0 -> j63, w7==32 -> j64
        const int jec = 63 + (ec >> 2);
        xh[1][p ^ 1][72 + jec] = (half_t)hec;
        if (s == T_STEPS) h1f[jec] = hec;
      }
    }

    // stage x_{s+1}; shift prefetch pipeline
    if (isW6 && (s + 1 < T_STEPS)) {
      half_t* dst = &xh[0][p ^ 1][0];
      dst[u] = (half_t)nxA;
      if (u == 0) dst[64] = (half_t)nxB;
      nxA = fA; nxB = fB;
    }
    __syncthreads();
  }

  // ---- output projection: out[b] = b_lin + h1_final . w_lin ----
  if (tid == 0) {
    float acc = blin[0];
    for (int jj = 0; jj < H; ++jj) acc += h1f[jj] * wlin[jj];
    out[b] = acc;
  }
}

extern "C" void kernel_launch(void* const* d_in, const int* in_sizes, int n_in,
                              void* d_out, int out_size, void* d_ws, size_t ws_size,
                              hipStream_t stream) {
  const float* x    = (const float*)d_in[0];
  const float* wih0 = (const float*)d_in[1];
  const float* whh0 = (const float*)d_in[2];
  const float* bih0 = (const float*)d_in[3];
  const float* bhh0 = (const float*)d_in[4];
  const float* wih1 = (const float*)d_in[5];
  const float* whh1 = (const float*)d_in[6];
  const float* bih1 = (const float*)d_in[7];
  const float* bhh1 = (const float*)d_in[8];
  const float* wlin = (const float*)d_in[9];
  const float* blin = (const float*)d_in[10];
  float* out = (float*)d_out;

  lstm_fused<<<512, 512, 0, stream>>>(x, wih0, whh0, bih0, bhh0,
                                      wih1, whh1, bih1, bhh1, wlin, blin, out);
}